// Round 14
// baseline (178.035 us; speedup 1.0000x reference)
//
#include <hip/hip_runtime.h>
#include <math.h>

#define GAMMA 0.05f
#define EPSBN 1e-5f

#define B_   128
#define H0   96
#define O1   32
#define P1   46   // pooled1 (46x46), conv1 out 92x92
#define O2   64
#define H2C  42   // conv2 out spatial
#define P2   21   // pooled2
#define FLAT (O2*P2*P2)   // 28224
#define L1N  256
#define NCLS 10
#define XW   104  // padded x8 row width

typedef __attribute__((ext_vector_type(8))) short bf16x8;
typedef __attribute__((ext_vector_type(4))) float f32x4;
typedef __attribute__((ext_vector_type(16))) float f32x16;

static __device__ __forceinline__ float bf2f(unsigned short h) {
    return __uint_as_float(((unsigned int)h) << 16);
}
static __device__ __forceinline__ unsigned short f2bf(float f) {
    unsigned int u = __float_as_uint(f);
    u = (u + 0x7FFFu + ((u >> 16) & 1u)) >> 16;
    return (unsigned short)u;
}

// ------- prep: w2bf[tap][ks][hi][o][8ch] bf16, w1p8[t][o][8ch], wsq1, wsq2 -------
__global__ void k_prep(const float* __restrict__ w1, const float* __restrict__ w2,
                       float* __restrict__ wsq1, float* __restrict__ wsq2,
                       unsigned short* __restrict__ w2bf, unsigned short* __restrict__ w1p8) {
    int t0 = blockIdx.x * 256 + threadIdx.x;
    for (int i = t0; i < 51200 + 28 * 32 * 8; i += gridDim.x * 256) {
        if (i < 51200) {
            int e = i & 7, o = (i >> 3) & 63, hi = (i >> 9) & 1, ks = (i >> 10) & 1, kp = i >> 11;
            int ch = ks * 16 + hi * 8 + e;
            w2bf[i] = f2bf(w2[((size_t)o * 32 + ch) * 25 + kp]);
        } else {
            int j = i - 51200;
            int ch = j & 7, o = (j >> 3) & 31, t = j >> 8;  // t 0..27
            float v = (t < 25 && ch < 3) ? w1[(size_t)(o * 3 + ch) * 25 + t] : 0.f;
            w1p8[j] = f2bf(v);
        }
    }
    if (blockIdx.x == 0) {
        int lt = threadIdx.x;
        if (lt < 32) {
            const float* p = w1 + lt * 75;
            float s = 0.f;
            for (int i = 0; i < 75; ++i) s += p[i] * p[i];
            wsq1[lt] = s;
        } else if (lt < 96) {
            const float* p = w2 + (size_t)(lt - 32) * 800;
            float s = 0.f;
            for (int i = 0; i < 800; ++i) s += p[i] * p[i];
            wsq2[lt - 32] = s;
        }
    }
}

// ------- x8[b][r][cc][8] bf16 (pad ch + pad cols>=96) AND ssum1[b][r][cc]=sum_c x^2 -------
__global__ void k_x8s(const float* __restrict__ x, unsigned short* __restrict__ x8,
                      float* __restrict__ ssum1) {
    int idx = blockIdx.x * 256 + threadIdx.x;
    if (idx >= B_ * H0 * XW) return;
    int cc = idx % XW;
    int t = idx / XW;
    int r = t % H0, b = t / H0;
    unsigned int p0 = 0, p1 = 0;
    if (cc < 96) {
        const float* xp = x + (size_t)b * 3 * 9216 + r * 96 + cc;
        float a = xp[0], c = xp[9216], d = xp[18432];
        p0 = (unsigned)f2bf(a) | ((unsigned)f2bf(c) << 16);
        p1 = (unsigned)f2bf(d);
        ssum1[(size_t)b * 9216 + r * 96 + cc] = a * a + c * c + d * d;
    }
    uint4 pk; pk.x = p0; pk.y = p1; pk.z = 0; pk.w = 0;
    *(uint4*)(x8 + (size_t)idx * 8) = pk;
}

// ------- separable 5x5 box sums (25 reads -> 5+5) -------
// rs1[b][96][92] = horiz 5-sum of ssum1[b][96][96]
__global__ void k_rs1(const float* __restrict__ ssum1, float* __restrict__ rs1) {
    int idx = blockIdx.x * 256 + threadIdx.x;
    if (idx >= B_ * 96 * 92) return;
    int j = idx % 92;
    int t = idx / 92;
    int r = t % 96, b = t / 96;
    const float* s = ssum1 + ((size_t)b * 96 + r) * 96 + j;
    rs1[idx] = s[0] + s[1] + s[2] + s[3] + s[4];
}
// xsq1[b][92][92] = vert 5-sum of rs1
__global__ void k_cs1(const float* __restrict__ rs1, float* __restrict__ xsq1) {
    int idx = blockIdx.x * 256 + threadIdx.x;
    if (idx >= B_ * 92 * 92) return;
    int j = idx % 92;
    int t = idx / 92;
    int i = t % 92, b = t / 92;
    const float* s = rs1 + ((size_t)b * 96 + i) * 92 + j;
    xsq1[idx] = s[0] + s[92] + s[184] + s[276] + s[368];
}
// rs2[b][46][42] = horiz 5-sum of ssum[b][46][46]
__global__ void k_rs2(const float* __restrict__ ssum, float* __restrict__ rs2) {
    int idx = blockIdx.x * 256 + threadIdx.x;
    if (idx >= B_ * 46 * 42) return;
    int j = idx % 42;
    int t = idx / 42;
    int r = t % 46, b = t / 46;
    const float* s = ssum + ((size_t)b * 46 + r) * 46 + j;
    rs2[idx] = s[0] + s[1] + s[2] + s[3] + s[4];
}
// xsq2[b][42][42] = vert 5-sum of rs2
__global__ void k_cs2(const float* __restrict__ rs2, float* __restrict__ xsq2) {
    int idx = blockIdx.x * 256 + threadIdx.x;
    if (idx >= B_ * H2C * H2C) return;
    int j = idx % H2C;
    int t = idx / H2C;
    int i = t % H2C, b = t / H2C;
    const float* s = rs2 + ((size_t)b * 46 + i) * 42 + j;
    xsq2[idx] = s[0] + s[42] + s[84] + s[126] + s[168];
}

// ------- conv1 MFMA v3: NO LDS -- direct global reads of x8 (L1-resident tile) -------
// One wave per pooled row: grid (46, B). h1t [b][46*46][32] bf16 + fused ssum.
// r13 post-mortem: LDS-tile+barrier structure was the common factor of all ~50us
// conv variants; per-block tile is L1-sized (21KB, high reuse) -> read direct.
__global__ __launch_bounds__(64, 2) void k_conv1m(
    const unsigned short* __restrict__ x8, const unsigned short* __restrict__ w1p8,
    const float* __restrict__ xsq1, const float* __restrict__ wsq1,
    const float* __restrict__ g, const float* __restrict__ bb_,
    const float* __restrict__ m, const float* __restrict__ v,
    unsigned short* __restrict__ h1t, float* __restrict__ ssum) {
    int b = blockIdx.y;
    int pi = blockIdx.x;
    int lane = threadIdx.x;
    int l15 = lane & 15, l4 = lane >> 4;
    const unsigned short* xb = x8 + (size_t)b * H0 * XW * 8;

    bf16x8 Bf[7][2];
    int kio[7], kjo[7];
    #pragma unroll
    for (int mm = 0; mm < 7; ++mm) {
        int t = mm * 4 + l4;  // 0..27
        kio[mm] = t / 5; kjo[mm] = t - kio[mm] * 5;
        #pragma unroll
        for (int nt = 0; nt < 2; ++nt)
            Bf[mm][nt] = *(const bf16x8*)(w1p8 + ((size_t)t * 32 + nt * 16 + l15) * 8);
    }
    float wqa[2], sca[2], moa[2], boa[2];
    #pragma unroll
    for (int nt = 0; nt < 2; ++nt) {
        int o = nt * 16 + l15;
        wqa[nt] = wsq1[o];
        sca[nt] = g[o] * rsqrtf(v[o] + EPSBN);
        moa[nt] = m[o]; boa[nt] = bb_[o];
    }

    for (int s6 = 0; s6 < 6; ++s6) {
        int j0 = s6 * 16;
        f32x4 a0[2], a1[2];
        #pragma unroll
        for (int nt = 0; nt < 2; ++nt) {
            a0[nt] = (f32x4){0.f, 0.f, 0.f, 0.f};
            a1[nt] = (f32x4){0.f, 0.f, 0.f, 0.f};
        }
        #pragma unroll
        for (int mm = 0; mm < 7; ++mm) {
            int row = 2 * pi + kio[mm]; if (row > 95) row = 95;  // pad-tap rows clamp (zero weight)
            bf16x8 av = *(const bf16x8*)(xb + ((size_t)row * XW + j0 + l15 + kjo[mm]) * 8);
            a0[0] = __builtin_amdgcn_mfma_f32_16x16x32_bf16(av, Bf[mm][0], a0[0], 0, 0, 0);
            a0[1] = __builtin_amdgcn_mfma_f32_16x16x32_bf16(av, Bf[mm][1], a0[1], 0, 0, 0);
        }
        #pragma unroll
        for (int mm = 0; mm < 7; ++mm) {
            int row = 2 * pi + 1 + kio[mm]; if (row > 95) row = 95;
            bf16x8 av = *(const bf16x8*)(xb + ((size_t)row * XW + j0 + l15 + kjo[mm]) * 8);
            a1[0] = __builtin_amdgcn_mfma_f32_16x16x32_bf16(av, Bf[mm][0], a1[0], 0, 0, 0);
            a1[1] = __builtin_amdgcn_mfma_f32_16x16x32_bf16(av, Bf[mm][1], a1[1], 0, 0, 0);
        }
        int i0 = 2 * pi;
        #pragma unroll
        for (int q = 0; q < 2; ++q) {
            int jc = j0 + l4 * 4 + 2 * q;      // conv col of left pool element
            int pj = (j0 >> 1) + l4 * 2 + q;   // pooled col
            if (pj < P1) {
                const float* xr = xsq1 + ((size_t)b * 92 + i0) * 92 + jc;
                float xv00 = xr[0], xv01 = xr[1], xv10 = xr[92], xv11 = xr[93];
                float s2 = 0.f;
                #pragma unroll
                for (int nt = 0; nt < 2; ++nt) {
                    float e00 = __expf(-GAMMA * (xv00 - 2.f * a0[nt][2 * q]     + wqa[nt]));
                    float e01 = __expf(-GAMMA * (xv01 - 2.f * a0[nt][2 * q + 1] + wqa[nt]));
                    float e10 = __expf(-GAMMA * (xv10 - 2.f * a1[nt][2 * q]     + wqa[nt]));
                    float e11 = __expf(-GAMMA * (xv11 - 2.f * a1[nt][2 * q + 1] + wqa[nt]));
                    float mx = fmaxf(fmaxf(e00, e01), fmaxf(e10, e11));
                    float y = (mx - moa[nt]) * sca[nt] + boa[nt];
                    unsigned short ob = f2bf(y);
                    h1t[((size_t)b * 2116 + pi * P1 + pj) * 32 + nt * 16 + l15] = ob;
                    float yb = bf2f(ob);
                    s2 = fmaf(yb, yb, s2);
                }
                s2 += __shfl_xor(s2, 1, 16);
                s2 += __shfl_xor(s2, 2, 16);
                s2 += __shfl_xor(s2, 4, 16);
                s2 += __shfl_xor(s2, 8, 16);
                if (l15 == 0) ssum[(size_t)b * 2116 + pi * P1 + pj] = s2;
            }
        }
    }
}

// ------- conv2 MFMA v12: NO LDS -- direct global A-reads from h1t -------
// One wave per (pooled row, image): grid (21, B). Per-wave tile (2 rows x 46 pos
// x 64B) is L1-resident with 4x (ks,hi)-slot reuse of each 64B line. No barrier,
// no ds ops -> global loads pipeline freely across ki iterations.
__global__ __launch_bounds__(64, 2) void k_conv2m(
    const unsigned short* __restrict__ h1t, const unsigned short* __restrict__ w2bf,
    const float* __restrict__ xsq2, const float* __restrict__ wsq2,
    const float* __restrict__ g2, const float* __restrict__ b2,
    const float* __restrict__ m2, const float* __restrict__ v2,
    unsigned short* __restrict__ h2t) {
    int b = blockIdx.y;
    int prow = blockIdx.x;           // 0..20
    int lane = threadIdx.x;
    int hi = lane >> 5;
    int ri = lane & 1;
    int cpos = (lane >> 1) & 15;
    int ol = lane & 31;
    const unsigned short* hb = h1t + (size_t)b * 2116 * 32;

    float wqA[2], scA[2], moA[2], boA[2];
    #pragma unroll
    for (int nt = 0; nt < 2; ++nt) {
        int o = nt * 32 + ol;
        wqA[nt] = wsq2[o];
        scA[nt] = g2[o] * rsqrtf(v2[o] + EPSBN);
        moA[nt] = m2[o]; boA[nt] = b2[o];
    }

    f32x16 acc0[3], acc1[3];
    #pragma unroll
    for (int cg = 0; cg < 3; ++cg)
        #pragma unroll
        for (int e = 0; e < 16; ++e) { acc0[cg][e] = 0.f; acc1[cg][e] = 0.f; }

    #pragma unroll 1
    for (int ks = 0; ks < 2; ++ks) {
        const unsigned short* wb0 = w2bf + (((size_t)ks * 2 + hi) * 64 + ol) * 8;
        const unsigned short* wb1 = wb0 + 32 * 8;   // o + 32
        int cslot = (2 * ks + hi) * 8;
        #pragma unroll 1
        for (int ki = 0; ki < 5; ++ki) {
            bf16x8 B0[5], B1[5];
            #pragma unroll
            for (int kj = 0; kj < 5; ++kj) {
                B0[kj] = *(const bf16x8*)(wb0 + (size_t)(ki * 5 + kj) * 2048);
                B1[kj] = *(const bf16x8*)(wb1 + (size_t)(ki * 5 + kj) * 2048);
            }
            int srow = 2 * prow + ri + ki; if (srow > 45) srow = 45;
            const unsigned short* arow = hb + (size_t)srow * 46 * 32 + cslot;
            #pragma unroll
            for (int cg = 0; cg < 3; ++cg) {
                #pragma unroll
                for (int kj = 0; kj < 5; ++kj) {
                    int jl = cg * 16 + cpos + kj; if (jl > 45) jl = 45;
                    bf16x8 av = *(const bf16x8*)(arow + (size_t)jl * 32);
                    acc0[cg] = __builtin_amdgcn_mfma_f32_32x32x16_bf16(av, B0[kj], acc0[cg], 0, 0, 0);
                    acc1[cg] = __builtin_amdgcn_mfma_f32_32x32x16_bf16(av, B1[kj], acc1[cg], 0, 0, 0);
                }
            }
        }
    }
    // epilogue: C row = (r&3) + 8*(r>>2) + 4*hi; pool window w = 2q+hi holds rows 4w..4w+3
    // h2t O-MAJOR: [b][o][441]
    size_t bb = (size_t)b * FLAT;
    #pragma unroll
    for (int cg = 0; cg < 3; ++cg) {
        int j0 = cg * 16;
        #pragma unroll
        for (int q = 0; q < 4; ++q) {
            int wdw = 2 * q + hi;
            int pcol = cg * 8 + wdw;
            if (pcol < P2) {
                const float* xs = xsq2 + ((size_t)b * H2C + 2 * prow) * H2C + j0 + 2 * wdw;
                float x00 = xs[0], x01 = xs[1], x10 = xs[H2C], x11 = xs[H2C + 1];
                int pp = prow * 21 + pcol;
                {
                    float d0 = x00 - 2.f * acc0[cg][4 * q + 0] + wqA[0];
                    float d1 = x10 - 2.f * acc0[cg][4 * q + 1] + wqA[0];
                    float d2 = x01 - 2.f * acc0[cg][4 * q + 2] + wqA[0];
                    float d3 = x11 - 2.f * acc0[cg][4 * q + 3] + wqA[0];
                    float dm = fminf(fminf(d0, d1), fminf(d2, d3));
                    float y = (__expf(-GAMMA * dm) - moA[0]) * scA[0] + boA[0];
                    h2t[bb + (size_t)ol * 441 + pp] = f2bf(y);
                }
                {
                    float d0 = x00 - 2.f * acc1[cg][4 * q + 0] + wqA[1];
                    float d1 = x10 - 2.f * acc1[cg][4 * q + 1] + wqA[1];
                    float d2 = x01 - 2.f * acc1[cg][4 * q + 2] + wqA[1];
                    float d3 = x11 - 2.f * acc1[cg][4 * q + 3] + wqA[1];
                    float dm = fminf(fminf(d0, d1), fminf(d2, d3));
                    float y = (__expf(-GAMMA * dm) - moA[1]) * scA[1] + boA[1];
                    h2t[bb + (size_t)(32 + ol) * 441 + pp] = f2bf(y);
                }
            }
        }
    }
}

// ------- FC1 MFMA v3: merged m-halves (halves W traffic), flat k'=o*441+p -------
// grid (63 ksegs, 4 nblocks), 256 thr. W staged fp32->bf16 in LDS (packed u32 writes).
__global__ __launch_bounds__(256) void k_fc1m(const unsigned short* __restrict__ A,
                                              const float* __restrict__ W,
                                              float* __restrict__ part) {
    __shared__ unsigned short Ws[64][456];
    int s = blockIdx.x;
    int nb = blockIdx.y;
    int n0 = nb * 64;
    int k0 = s * 448;
    int tid = threadIdx.x;
    for (int i = tid; i < 64 * 112; i += 256) {
        int n = i / 112, j = i - n * 112;
        float4 v = *(const float4*)(W + (size_t)(n0 + n) * FLAT + k0 + j * 4);
        unsigned int lo = (unsigned)f2bf(v.x) | ((unsigned)f2bf(v.y) << 16);
        unsigned int hi2 = (unsigned)f2bf(v.z) | ((unsigned)f2bf(v.w) << 16);
        uint2 pk; pk.x = lo; pk.y = hi2;
        *(uint2*)(&Ws[n][j * 4]) = pk;
    }
    __syncthreads();
    int lane = tid & 63, w = tid >> 6;
    int l15 = lane & 15, l4 = lane >> 4;
    const unsigned short* ap = A + (size_t)l15 * FLAT + k0 + l4 * 8;
    f32x4 acc[8];
    #pragma unroll
    for (int mf = 0; mf < 8; ++mf) acc[mf] = (f32x4){0.f, 0.f, 0.f, 0.f};
    #pragma unroll 2
    for (int kc = 0; kc < 14; ++kc) {
        bf16x8 Bf = *(const bf16x8*)(&Ws[w * 16 + l15][kc * 32 + l4 * 8]);
        #pragma unroll
        for (int mf = 0; mf < 8; ++mf) {
            bf16x8 Af = *(const bf16x8*)(ap + (size_t)mf * 16 * FLAT + kc * 32);
            acc[mf] = __builtin_amdgcn_mfma_f32_16x16x32_bf16(Af, Bf, acc[mf], 0, 0, 0);
        }
    }
    float* pp = part + (size_t)s * B_ * L1N;
    #pragma unroll
    for (int mf = 0; mf < 8; ++mf)
        #pragma unroll
        for (int r = 0; r < 4; ++r)
            pp[(size_t)(mf * 16 + l4 * 4 + r) * L1N + n0 + w * 16 + l15] = acc[mf][r];
}

// ---------------- FC1 reduce + bias + relu ----------------
__global__ void k_fc1red(const float* __restrict__ part, const float* __restrict__ bias,
                         float* __restrict__ fc1o) {
    int idx = blockIdx.x * blockDim.x + threadIdx.x;
    if (idx >= B_ * L1N) return;
    int o = idx & (L1N - 1);
    float s = 0.f;
    for (int ks = 0; ks < 63; ++ks) s += part[(size_t)ks * B_ * L1N + idx];
    fc1o[idx] = fmaxf(s + bias[o], 0.f);
}

// ---------------- FC2 + relu + log_softmax ----------------
__global__ void k_fc2(const float* __restrict__ a, const float* __restrict__ w,
                      const float* __restrict__ bias, float* __restrict__ out) {
    int b = blockIdx.x;
    int lane = threadIdx.x;  // 64
    __shared__ float z[NCLS];
    for (int j = 0; j < NCLS; ++j) {
        float p = 0.f;
        for (int k = lane; k < L1N; k += 64)
            p = fmaf(a[(size_t)b * L1N + k], w[(size_t)j * L1N + k], p);
        #pragma unroll
        for (int off = 32; off; off >>= 1) p += __shfl_down(p, off, 64);
        if (lane == 0) z[j] = fmaxf(p + bias[j], 0.f);
    }
    __syncthreads();
    if (lane == 0) {
        float mx = -1e30f;
        for (int j = 0; j < NCLS; ++j) mx = fmaxf(mx, z[j]);
        float s = 0.f;
        for (int j = 0; j < NCLS; ++j) s += expf(z[j] - mx);
        float l = logf(s);
        for (int j = 0; j < NCLS; ++j) out[(size_t)b * NCLS + j] = z[j] - mx - l;
    }
}

extern "C" void kernel_launch(void* const* d_in, const int* in_sizes, int n_in,
                              void* d_out, int out_size, void* d_ws, size_t ws_size,
                              hipStream_t stream) {
    const float* x    = (const float*)d_in[0];
    const float* w1   = (const float*)d_in[1];
    const float* w2   = (const float*)d_in[2];
    const float* bn1g = (const float*)d_in[3];
    const float* bn1b = (const float*)d_in[4];
    const float* bn1m = (const float*)d_in[5];
    const float* bn1v = (const float*)d_in[6];
    const float* bn2g = (const float*)d_in[7];
    const float* bn2b = (const float*)d_in[8];
    const float* bn2m = (const float*)d_in[9];
    const float* bn2v = (const float*)d_in[10];
    const float* fc1w = (const float*)d_in[11];
    const float* fc1b = (const float*)d_in[12];
    const float* fc2w = (const float*)d_in[13];
    const float* fc2b = (const float*)d_in[14];
    float* out = (float*)d_out;

    char* wsb = (char*)d_ws;
    unsigned short* h1t = (unsigned short*)wsb;  wsb += (size_t)B_ * 2116 * 32 * 2;     // 17.3 MB
    unsigned short* x8  = (unsigned short*)wsb;  wsb += (size_t)B_ * H0 * XW * 8 * 2;   // 20.4 MB
    float* ssum1 = (float*)wsb;                  wsb += (size_t)B_ * 9216 * 4;          // 4.7 MB
    float* rs1   = (float*)wsb;                  wsb += (size_t)B_ * 96 * 92 * 4;       // 4.5 MB
    float* xsq1  = (float*)wsb;                  wsb += (size_t)B_ * 92 * 92 * 4;       // 4.3 MB
    float* ssum  = (float*)wsb;                  wsb += (size_t)B_ * 2116 * 4;          // 1.1 MB
    float* rs2   = (float*)wsb;                  wsb += (size_t)B_ * 46 * 42 * 4;       // 1.0 MB
    float* xsq2  = (float*)wsb;                  wsb += (size_t)B_ * H2C * H2C * 4;     // 0.9 MB
    unsigned short* h2t = (unsigned short*)wsb;  wsb += (size_t)B_ * FLAT * 2;          // 7.2 MB (o-major)
    float* part  = (float*)wsb;                  wsb += (size_t)63 * B_ * L1N * 4;      // 8.3 MB
    float* fc1o  = (float*)wsb;                  wsb += (size_t)B_ * L1N * 4;
    unsigned short* w2bf = (unsigned short*)wsb; wsb += (size_t)51200 * 2;
    unsigned short* w1p8 = (unsigned short*)wsb; wsb += (size_t)28 * 32 * 8 * 2;
    float* wsq1 = (float*)wsb;                   wsb += 32 * 4;
    float* wsq2 = (float*)wsb;                   wsb += 64 * 4;

    k_prep<<<64, 256, 0, stream>>>(w1, w2, wsq1, wsq2, w2bf, w1p8);
    k_x8s<<<(B_ * H0 * XW + 255) / 256, 256, 0, stream>>>(x, x8, ssum1);
    k_rs1<<<(B_ * 96 * 92 + 255) / 256, 256, 0, stream>>>(ssum1, rs1);
    k_cs1<<<(B_ * 92 * 92 + 255) / 256, 256, 0, stream>>>(rs1, xsq1);
    k_conv1m<<<dim3(P1, B_), 64, 0, stream>>>(
        x8, w1p8, xsq1, wsq1, bn1g, bn1b, bn1m, bn1v, h1t, ssum);
    k_rs2<<<(B_ * 46 * 42 + 255) / 256, 256, 0, stream>>>(ssum, rs2);
    k_cs2<<<(B_ * H2C * H2C + 255) / 256, 256, 0, stream>>>(rs2, xsq2);
    k_conv2m<<<dim3(P2, B_), 64, 0, stream>>>(
        h1t, w2bf, xsq2, wsq2, bn2g, bn2b, bn2m, bn2v, h2t);
    k_fc1m<<<dim3(63, 4), 256, 0, stream>>>(h2t, fc1w, part);
    k_fc1red<<<(B_ * L1N + 255) / 256, 256, 0, stream>>>(part, fc1b, fc1o);
    k_fc2<<<B_, 64, 0, stream>>>(fc1o, fc2w, fc2b, out);
}

// Round 15
// 135.654 us; speedup vs baseline: 1.3124x; 1.3124x over previous
//
#include <hip/hip_runtime.h>
#include <math.h>

#define GAMMA 0.05f
#define EPSBN 1e-5f

#define B_   128
#define H0   96
#define O1   32
#define P1   46   // pooled1 (46x46), conv1 out 92x92
#define O2   64
#define H2C  42   // conv2 out spatial
#define P2   21   // pooled2
#define FLAT (O2*P2*P2)   // 28224
#define L1N  256
#define NCLS 10
#define XW   104  // padded x8 row width

typedef __attribute__((ext_vector_type(8))) short bf16x8;
typedef __attribute__((ext_vector_type(4))) float f32x4;
typedef __attribute__((ext_vector_type(16))) float f32x16;

static __device__ __forceinline__ float bf2f(unsigned short h) {
    return __uint_as_float(((unsigned int)h) << 16);
}
static __device__ __forceinline__ unsigned short f2bf(float f) {
    unsigned int u = __float_as_uint(f);
    u = (u + 0x7FFFu + ((u >> 16) & 1u)) >> 16;
    return (unsigned short)u;
}

// ------- prep: w2bf = -2*w2 (tap,ks,hi,o,8ch); w1p8 = -2*w1 with ch3=1 (xsq fusion) -------
// MFMA then accumulates  -2*cross + xsq  directly: A ch3 carries s = sum_c x^2.
__global__ void k_prep(const float* __restrict__ w1, const float* __restrict__ w2,
                       float* __restrict__ wsq1, float* __restrict__ wsq2,
                       unsigned short* __restrict__ w2bf, unsigned short* __restrict__ w1p8) {
    int t0 = blockIdx.x * 256 + threadIdx.x;
    for (int i = t0; i < 51200 + 28 * 32 * 8; i += gridDim.x * 256) {
        if (i < 51200) {
            int e = i & 7, o = (i >> 3) & 63, hi = (i >> 9) & 1, ks = (i >> 10) & 1, kp = i >> 11;
            int ch = ks * 16 + hi * 8 + e;
            w2bf[i] = f2bf(-2.f * w2[((size_t)o * 32 + ch) * 25 + kp]);
        } else {
            int j = i - 51200;
            int ch = j & 7, o = (j >> 3) & 31, t = j >> 8;  // t 0..27
            float v = 0.f;
            if (t < 25) {
                if (ch < 3) v = -2.f * w1[(size_t)(o * 3 + ch) * 25 + t];
                else if (ch == 3) v = 1.f;   // xsq-fusion channel
            }
            w1p8[j] = f2bf(v);
        }
    }
    if (blockIdx.x == 0) {
        int lt = threadIdx.x;
        if (lt < 32) {
            const float* p = w1 + lt * 75;
            float s = 0.f;
            for (int i = 0; i < 75; ++i) s += p[i] * p[i];
            wsq1[lt] = s;
        } else if (lt < 96) {
            const float* p = w2 + (size_t)(lt - 32) * 800;
            float s = 0.f;
            for (int i = 0; i < 800; ++i) s += p[i] * p[i];
            wsq2[lt - 32] = s;
        }
    }
}

// ------- x8[b][r][cc][8] bf16: ch0-2 = x, ch3 = sum_c x^2, rest 0; pad cols >= 96 -------
__global__ void k_x8s(const float* __restrict__ x, unsigned short* __restrict__ x8) {
    int idx = blockIdx.x * 256 + threadIdx.x;
    if (idx >= B_ * H0 * XW) return;
    int cc = idx % XW;
    int t = idx / XW;
    int r = t % H0, b = t / H0;
    unsigned int p0 = 0, p1 = 0;
    if (cc < 96) {
        const float* xp = x + (size_t)b * 3 * 9216 + r * 96 + cc;
        float a = xp[0], c = xp[9216], dd = xp[18432];
        float s = a * a + c * c + dd * dd;
        p0 = (unsigned)f2bf(a) | ((unsigned)f2bf(c) << 16);
        p1 = (unsigned)f2bf(dd) | ((unsigned)f2bf(s) << 16);
    }
    uint4 pk; pk.x = p0; pk.y = p1; pk.z = 0; pk.w = 0;
    *(uint4*)(x8 + (size_t)idx * 8) = pk;
}

// ------- separable 5x5 box sums for conv2's xsq (cheap; K slots full, can't fuse) -------
// rs2[b][46][42] = horiz 5-sum of ssum[b][46][46]
__global__ void k_rs2(const float* __restrict__ ssum, float* __restrict__ rs2) {
    int idx = blockIdx.x * 256 + threadIdx.x;
    if (idx >= B_ * 46 * 42) return;
    int j = idx % 42;
    int t = idx / 42;
    int r = t % 46, b = t / 46;
    const float* s = ssum + ((size_t)b * 46 + r) * 46 + j;
    rs2[idx] = s[0] + s[1] + s[2] + s[3] + s[4];
}
// xsq2[b][42][42] = vert 5-sum of rs2
__global__ void k_cs2(const float* __restrict__ rs2, float* __restrict__ xsq2) {
    int idx = blockIdx.x * 256 + threadIdx.x;
    if (idx >= B_ * H2C * H2C) return;
    int j = idx % H2C;
    int t = idx / H2C;
    int i = t % H2C, b = t / H2C;
    const float* s = rs2 + ((size_t)b * 46 + i) * 42 + j;
    xsq2[idx] = s[0] + s[42] + s[84] + s[126] + s[168];
}

// ------- conv1 MFMA v4: LDS-batched (r12 structure), xsq fused into MFMA -------
// acc = -2*cross + xsq (via ch3); d = acc + wsq; pool via min-d -> ONE exp.
// h1t [b][46*46][32] bf16 + fused ssum epilogue.
__global__ __launch_bounds__(256) void k_conv1m(
    const unsigned short* __restrict__ x8, const unsigned short* __restrict__ w1p8,
    const float* __restrict__ wsq1,
    const float* __restrict__ g, const float* __restrict__ bb_,
    const float* __restrict__ m, const float* __restrict__ v,
    unsigned short* __restrict__ h1t, float* __restrict__ ssum) {
    __shared__ unsigned short xt[1536 * 8];  // 24576 B (valid 13*104=1352 chunks)
    int b = blockIdx.y;
    int pi0 = blockIdx.x * 4;
    int tid = threadIdx.x;
    {
        uint4 tmp[6];
        #pragma unroll
        for (int it = 0; it < 6; ++it) {
            int c = tid + it * 256;
            int cs = c < 1352 ? c : 1351;
            int rr = cs / XW, cc2 = cs - rr * XW;
            int srow = 2 * pi0 + rr; if (srow > 95) srow = 95;
            tmp[it] = *(const uint4*)(x8 + (((size_t)b * H0 + srow) * XW + cc2) * 8);
        }
        #pragma unroll
        for (int it = 0; it < 6; ++it) {
            int c = tid + it * 256;
            *(uint4*)(xt + (size_t)c * 8) = tmp[it];
        }
    }
    __syncthreads();
    int w = tid >> 6, lane = tid & 63;
    int pi = pi0 + w;
    if (pi >= P1) return;
    int l15 = lane & 15, l4 = lane >> 4;

    bf16x8 Bf[7][2];
    int kio[7], kjo[7];
    #pragma unroll
    for (int mm = 0; mm < 7; ++mm) {
        int t = mm * 4 + l4;  // 0..27
        kio[mm] = t / 5; kjo[mm] = t - kio[mm] * 5;
        #pragma unroll
        for (int nt = 0; nt < 2; ++nt)
            Bf[mm][nt] = *(const bf16x8*)(w1p8 + ((size_t)t * 32 + nt * 16 + l15) * 8);
    }
    float wqa[2], sca[2], moa[2], boa[2];
    #pragma unroll
    for (int nt = 0; nt < 2; ++nt) {
        int o = nt * 16 + l15;
        wqa[nt] = wsq1[o];
        sca[nt] = g[o] * rsqrtf(v[o] + EPSBN);
        moa[nt] = m[o]; boa[nt] = bb_[o];
    }

    for (int s6 = 0; s6 < 6; ++s6) {
        int j0 = s6 * 16;
        f32x4 a0[2], a1[2];
        #pragma unroll
        for (int nt = 0; nt < 2; ++nt) {
            a0[nt] = (f32x4){0.f, 0.f, 0.f, 0.f};
            a1[nt] = (f32x4){0.f, 0.f, 0.f, 0.f};
        }
        {
            int ri = 2 * w;
            #pragma unroll
            for (int mm = 0; mm < 7; ++mm) {
                bf16x8 av = *(const bf16x8*)(xt + ((size_t)(ri + kio[mm]) * XW + j0 + l15 + kjo[mm]) * 8);
                a0[0] = __builtin_amdgcn_mfma_f32_16x16x32_bf16(av, Bf[mm][0], a0[0], 0, 0, 0);
                a0[1] = __builtin_amdgcn_mfma_f32_16x16x32_bf16(av, Bf[mm][1], a0[1], 0, 0, 0);
            }
            ri = 2 * w + 1;
            #pragma unroll
            for (int mm = 0; mm < 7; ++mm) {
                bf16x8 av = *(const bf16x8*)(xt + ((size_t)(ri + kio[mm]) * XW + j0 + l15 + kjo[mm]) * 8);
                a1[0] = __builtin_amdgcn_mfma_f32_16x16x32_bf16(av, Bf[mm][0], a1[0], 0, 0, 0);
                a1[1] = __builtin_amdgcn_mfma_f32_16x16x32_bf16(av, Bf[mm][1], a1[1], 0, 0, 0);
            }
        }
        #pragma unroll
        for (int q = 0; q < 2; ++q) {
            int pj = (j0 >> 1) + l4 * 2 + q;   // pooled col
            if (pj < P1) {
                float s2 = 0.f;
                #pragma unroll
                for (int nt = 0; nt < 2; ++nt) {
                    float d00 = a0[nt][2 * q]     + wqa[nt];
                    float d01 = a0[nt][2 * q + 1] + wqa[nt];
                    float d10 = a1[nt][2 * q]     + wqa[nt];
                    float d11 = a1[nt][2 * q + 1] + wqa[nt];
                    float dm = fminf(fminf(d00, d01), fminf(d10, d11));
                    float y = (__expf(-GAMMA * dm) - moa[nt]) * sca[nt] + boa[nt];
                    unsigned short ob = f2bf(y);
                    h1t[((size_t)b * 2116 + pi * P1 + pj) * 32 + nt * 16 + l15] = ob;
                    float yb = bf2f(ob);
                    s2 = fmaf(yb, yb, s2);
                }
                s2 += __shfl_xor(s2, 1, 16);
                s2 += __shfl_xor(s2, 2, 16);
                s2 += __shfl_xor(s2, 4, 16);
                s2 += __shfl_xor(s2, 8, 16);
                if (l15 == 0) ssum[(size_t)b * 2116 + pi * P1 + pj] = s2;
            }
        }
    }
}

// ------- conv2 MFMA: REVERTED to r12 v11 (best known, 49.7us, no spill) -------
// Only change: w2bf holds -2*w2, so d = xsq + acc + wsq (sign flip in epilogue).
// r14 lesson: (64,2) no-LDS variant re-triggered allocator spill (WRITE 56MB).
__global__ __launch_bounds__(256, 2) void k_conv2m(
    const unsigned short* __restrict__ h1t, const unsigned short* __restrict__ w2bf,
    const float* __restrict__ xsq2, const float* __restrict__ wsq2,
    const float* __restrict__ g2, const float* __restrict__ b2,
    const float* __restrict__ m2, const float* __restrict__ v2,
    unsigned short* __restrict__ h2t) {
    __shared__ unsigned short lds[2304 * 8];  // 36864 B (valid 12*46*4=2208 chunks)
    int b = blockIdx.y;
    int bx = blockIdx.x;             // 0..5: pooled rows 4bx..4bx+3
    int rbase = 8 * bx;
    int tid = threadIdx.x;
    {
        uint4 tmp[9];
        #pragma unroll
        for (int it = 0; it < 9; ++it) {
            int c = tid + it * 256;
            int cs = c < 2208 ? c : 2207;
            int p = cs >> 2, s = cs & 3;
            int il = p / 46, jl = p - il * 46;
            int srow = rbase + il; if (srow > 45) srow = 45;
            int src_s = (s - il - jl) & 3;  // inverse swizzle on SOURCE side
            tmp[it] = *(const uint4*)(h1t + ((((size_t)b * 46 + srow) * 46 + jl) * 32) + src_s * 8);
        }
        #pragma unroll
        for (int it = 0; it < 9; ++it) {
            int c = tid + it * 256;
            *(uint4*)(lds + (size_t)c * 8) = tmp[it];
        }
    }
    __syncthreads();

    int lane = tid & 63, st = tid >> 6;   // 4 waves, one pooled row each
    int prow = 4 * bx + st;
    if (prow >= P2) return;
    int hi = lane >> 5;
    int ri = lane & 1;
    int cpos = (lane >> 1) & 15;
    int ol = lane & 31;

    float wqA[2], scA[2], moA[2], boA[2];
    #pragma unroll
    for (int nt = 0; nt < 2; ++nt) {
        int o = nt * 32 + ol;
        wqA[nt] = wsq2[o];
        scA[nt] = g2[o] * rsqrtf(v2[o] + EPSBN);
        moA[nt] = m2[o]; boA[nt] = b2[o];
    }

    f32x16 acc0[3], acc1[3];
    #pragma unroll
    for (int cg = 0; cg < 3; ++cg)
        #pragma unroll
        for (int e = 0; e < 16; ++e) { acc0[cg][e] = 0.f; acc1[cg][e] = 0.f; }

    #pragma unroll 1
    for (int ks = 0; ks < 2; ++ks) {
        const unsigned short* wb0 = w2bf + (((size_t)ks * 2 + hi) * 64 + ol) * 8;
        const unsigned short* wb1 = wb0 + 32 * 8;   // o + 32
        int sB = 2 * ks + hi;
        #pragma unroll 1
        for (int ki = 0; ki < 5; ++ki) {
            bf16x8 B0[5], B1[5];
            #pragma unroll
            for (int kj = 0; kj < 5; ++kj) {
                B0[kj] = *(const bf16x8*)(wb0 + (size_t)(ki * 5 + kj) * 2048);
                B1[kj] = *(const bf16x8*)(wb1 + (size_t)(ki * 5 + kj) * 2048);
            }
            int il = 2 * st + ri + ki;   // 0..11 local row
            int base = il * 46;
            int sI = sB + il;
            #pragma unroll
            for (int cg = 0; cg < 3; ++cg) {
                #pragma unroll
                for (int kj = 0; kj < 5; ++kj) {
                    int jl = cg * 16 + cpos + kj; if (jl > 45) jl = 45;
                    int slot = (sI + jl) & 3;
                    bf16x8 av = *(const bf16x8*)(lds + (base + jl) * 32 + slot * 8);
                    acc0[cg] = __builtin_amdgcn_mfma_f32_32x32x16_bf16(av, B0[kj], acc0[cg], 0, 0, 0);
                    acc1[cg] = __builtin_amdgcn_mfma_f32_32x32x16_bf16(av, B1[kj], acc1[cg], 0, 0, 0);
                }
            }
        }
    }
    // epilogue: C row = (r&3) + 8*(r>>2) + 4*hi; pool window w = 2q+hi; d = xsq + acc + wsq
    size_t bb = (size_t)b * FLAT;
    #pragma unroll
    for (int cg = 0; cg < 3; ++cg) {
        int j0 = cg * 16;
        #pragma unroll
        for (int q = 0; q < 4; ++q) {
            int wdw = 2 * q + hi;
            int pcol = cg * 8 + wdw;
            if (pcol < P2) {
                const float* xs = xsq2 + ((size_t)b * H2C + 2 * prow) * H2C + j0 + 2 * wdw;
                float x00 = xs[0], x01 = xs[1], x10 = xs[H2C], x11 = xs[H2C + 1];
                int pp = prow * 21 + pcol;
                {
                    float d0 = x00 + acc0[cg][4 * q + 0] + wqA[0];
                    float d1 = x10 + acc0[cg][4 * q + 1] + wqA[0];
                    float d2 = x01 + acc0[cg][4 * q + 2] + wqA[0];
                    float d3 = x11 + acc0[cg][4 * q + 3] + wqA[0];
                    float dm = fminf(fminf(d0, d1), fminf(d2, d3));
                    float y = (__expf(-GAMMA * dm) - moA[0]) * scA[0] + boA[0];
                    h2t[bb + (size_t)ol * 441 + pp] = f2bf(y);
                }
                {
                    float d0 = x00 + acc1[cg][4 * q + 0] + wqA[1];
                    float d1 = x10 + acc1[cg][4 * q + 1] + wqA[1];
                    float d2 = x01 + acc1[cg][4 * q + 2] + wqA[1];
                    float d3 = x11 + acc1[cg][4 * q + 3] + wqA[1];
                    float dm = fminf(fminf(d0, d1), fminf(d2, d3));
                    float y = (__expf(-GAMMA * dm) - moA[1]) * scA[1] + boA[1];
                    h2t[bb + (size_t)(32 + ol) * 441 + pp] = f2bf(y);
                }
            }
        }
    }
}

// ------- FC1 MFMA v3: merged m-halves, flat k'=o*441+p (h2t o-major) -------
__global__ __launch_bounds__(256) void k_fc1m(const unsigned short* __restrict__ A,
                                              const float* __restrict__ W,
                                              float* __restrict__ part) {
    __shared__ unsigned short Ws[64][456];
    int s = blockIdx.x;
    int nb = blockIdx.y;
    int n0 = nb * 64;
    int k0 = s * 448;
    int tid = threadIdx.x;
    for (int i = tid; i < 64 * 112; i += 256) {
        int n = i / 112, j = i - n * 112;
        float4 v = *(const float4*)(W + (size_t)(n0 + n) * FLAT + k0 + j * 4);
        unsigned int lo = (unsigned)f2bf(v.x) | ((unsigned)f2bf(v.y) << 16);
        unsigned int hi2 = (unsigned)f2bf(v.z) | ((unsigned)f2bf(v.w) << 16);
        uint2 pk; pk.x = lo; pk.y = hi2;
        *(uint2*)(&Ws[n][j * 4]) = pk;
    }
    __syncthreads();
    int lane = tid & 63, w = tid >> 6;
    int l15 = lane & 15, l4 = lane >> 4;
    const unsigned short* ap = A + (size_t)l15 * FLAT + k0 + l4 * 8;
    f32x4 acc[8];
    #pragma unroll
    for (int mf = 0; mf < 8; ++mf) acc[mf] = (f32x4){0.f, 0.f, 0.f, 0.f};
    #pragma unroll 2
    for (int kc = 0; kc < 14; ++kc) {
        bf16x8 Bf = *(const bf16x8*)(&Ws[w * 16 + l15][kc * 32 + l4 * 8]);
        #pragma unroll
        for (int mf = 0; mf < 8; ++mf) {
            bf16x8 Af = *(const bf16x8*)(ap + (size_t)mf * 16 * FLAT + kc * 32);
            acc[mf] = __builtin_amdgcn_mfma_f32_16x16x32_bf16(Af, Bf, acc[mf], 0, 0, 0);
        }
    }
    float* pp = part + (size_t)s * B_ * L1N;
    #pragma unroll
    for (int mf = 0; mf < 8; ++mf)
        #pragma unroll
        for (int r = 0; r < 4; ++r)
            pp[(size_t)(mf * 16 + l4 * 4 + r) * L1N + n0 + w * 16 + l15] = acc[mf][r];
}

// ---------------- FC1 reduce + bias + relu ----------------
__global__ void k_fc1red(const float* __restrict__ part, const float* __restrict__ bias,
                         float* __restrict__ fc1o) {
    int idx = blockIdx.x * blockDim.x + threadIdx.x;
    if (idx >= B_ * L1N) return;
    int o = idx & (L1N - 1);
    float s = 0.f;
    for (int ks = 0; ks < 63; ++ks) s += part[(size_t)ks * B_ * L1N + idx];
    fc1o[idx] = fmaxf(s + bias[o], 0.f);
}

// ---------------- FC2 + relu + log_softmax ----------------
__global__ void k_fc2(const float* __restrict__ a, const float* __restrict__ w,
                      const float* __restrict__ bias, float* __restrict__ out) {
    int b = blockIdx.x;
    int lane = threadIdx.x;  // 64
    __shared__ float z[NCLS];
    for (int j = 0; j < NCLS; ++j) {
        float p = 0.f;
        for (int k = lane; k < L1N; k += 64)
            p = fmaf(a[(size_t)b * L1N + k], w[(size_t)j * L1N + k], p);
        #pragma unroll
        for (int off = 32; off; off >>= 1) p += __shfl_down(p, off, 64);
        if (lane == 0) z[j] = fmaxf(p + bias[j], 0.f);
    }
    __syncthreads();
    if (lane == 0) {
        float mx = -1e30f;
        for (int j = 0; j < NCLS; ++j) mx = fmaxf(mx, z[j]);
        float s = 0.f;
        for (int j = 0; j < NCLS; ++j) s += expf(z[j] - mx);
        float l = logf(s);
        for (int j = 0; j < NCLS; ++j) out[(size_t)b * NCLS + j] = z[j] - mx - l;
    }
}

extern "C" void kernel_launch(void* const* d_in, const int* in_sizes, int n_in,
                              void* d_out, int out_size, void* d_ws, size_t ws_size,
                              hipStream_t stream) {
    const float* x    = (const float*)d_in[0];
    const float* w1   = (const float*)d_in[1];
    const float* w2   = (const float*)d_in[2];
    const float* bn1g = (const float*)d_in[3];
    const float* bn1b = (const float*)d_in[4];
    const float* bn1m = (const float*)d_in[5];
    const float* bn1v = (const float*)d_in[6];
    const float* bn2g = (const float*)d_in[7];
    const float* bn2b = (const float*)d_in[8];
    const float* bn2m = (const float*)d_in[9];
    const float* bn2v = (const float*)d_in[10];
    const float* fc1w = (const float*)d_in[11];
    const float* fc1b = (const float*)d_in[12];
    const float* fc2w = (const float*)d_in[13];
    const float* fc2b = (const float*)d_in[14];
    float* out = (float*)d_out;

    char* wsb = (char*)d_ws;
    unsigned short* h1t = (unsigned short*)wsb;  wsb += (size_t)B_ * 2116 * 32 * 2;     // 17.3 MB
    unsigned short* x8  = (unsigned short*)wsb;  wsb += (size_t)B_ * H0 * XW * 8 * 2;   // 20.4 MB
    float* ssum  = (float*)wsb;                  wsb += (size_t)B_ * 2116 * 4;          // 1.1 MB
    float* rs2   = (float*)wsb;                  wsb += (size_t)B_ * 46 * 42 * 4;       // 1.0 MB
    float* xsq2  = (float*)wsb;                  wsb += (size_t)B_ * H2C * H2C * 4;     // 0.9 MB
    unsigned short* h2t = (unsigned short*)wsb;  wsb += (size_t)B_ * FLAT * 2;          // 7.2 MB (o-major)
    float* part  = (float*)wsb;                  wsb += (size_t)63 * B_ * L1N * 4;      // 8.3 MB
    float* fc1o  = (float*)wsb;                  wsb += (size_t)B_ * L1N * 4;
    unsigned short* w2bf = (unsigned short*)wsb; wsb += (size_t)51200 * 2;
    unsigned short* w1p8 = (unsigned short*)wsb; wsb += (size_t)28 * 32 * 8 * 2;
    float* wsq1 = (float*)wsb;                   wsb += 32 * 4;
    float* wsq2 = (float*)wsb;                   wsb += 64 * 4;

    k_prep<<<64, 256, 0, stream>>>(w1, w2, wsq1, wsq2, w2bf, w1p8);
    k_x8s<<<(B_ * H0 * XW + 255) / 256, 256, 0, stream>>>(x, x8);
    k_conv1m<<<dim3(12, B_), 256, 0, stream>>>(
        x8, w1p8, wsq1, bn1g, bn1b, bn1m, bn1v, h1t, ssum);
    k_rs2<<<(B_ * 46 * 42 + 255) / 256, 256, 0, stream>>>(ssum, rs2);
    k_cs2<<<(B_ * H2C * H2C + 255) / 256, 256, 0, stream>>>(rs2, xsq2);
    k_conv2m<<<dim3(6, B_), 256, 0, stream>>>(
        h1t, w2bf, xsq2, wsq2, bn2g, bn2b, bn2m, bn2v, h2t);
    k_fc1m<<<dim3(63, 4), 256, 0, stream>>>(h2t, fc1w, part);
    k_fc1red<<<(B_ * L1N + 255) / 256, 256, 0, stream>>>(part, fc1b, fc1o);
    k_fc2<<<B_, 64, 0, stream>>>(fc1o, fc2w, fc2b, out);
}